// Round 1
// baseline (1131.905 us; speedup 1.0000x reference)
//
#include <hip/hip_runtime.h>
#include <hip/hip_bf16.h>
#include <math.h>

#define B_ 2
#define L_ 1024
#define H_ 1024
#define D_ 2048
#define N_ 16
#define R_ 64

__device__ __forceinline__ float siluf(float g) {
    return g / (1.0f + __expf(-g));
}

// C[M,N] = A[M,K] @ B[N,K]^T  (both row-major, K contiguous)
// EPI: 0 = plain store, 1 = atomicAdd (K-split), 2 = softplus(acc + bias[col])
// 128x128 tile, BK=8, 256 threads, 8x8 per thread.
template<int EPI>
__global__ __launch_bounds__(256) void gemm_nt(
    const float* __restrict__ A, const float* __restrict__ Bm, float* __restrict__ C,
    int M, int N, int K, int lda, int ldb, int ldc, int kChunk,
    const float* __restrict__ bias)
{
    __shared__ float As[8][132];
    __shared__ float Bs[8][132];
    const int tid = threadIdx.x;
    const int m0 = blockIdx.y * 128;
    const int n0 = blockIdx.x * 128;
    const int k0 = blockIdx.z * kChunk;
    const int kEnd = min(K, k0 + kChunk);
    const int tx = tid & 15;        // col group
    const int ty = tid >> 4;        // row group
    const int lrow = tid >> 1;      // 0..127 staging row
    const int lk = (tid & 1) * 4;   // 0 or 4

    float acc[8][8];
#pragma unroll
    for (int i = 0; i < 8; i++)
#pragma unroll
        for (int j = 0; j < 8; j++) acc[i][j] = 0.f;

    for (int kt = k0; kt < kEnd; kt += 8) {
        float4 a4 = *(const float4*)(A + (size_t)(m0 + lrow) * lda + kt + lk);
        float4 b4 = make_float4(0.f, 0.f, 0.f, 0.f);
        if (n0 + lrow < N)
            b4 = *(const float4*)(Bm + (size_t)(n0 + lrow) * ldb + kt + lk);
        __syncthreads();
        As[lk + 0][lrow] = a4.x; As[lk + 1][lrow] = a4.y;
        As[lk + 2][lrow] = a4.z; As[lk + 3][lrow] = a4.w;
        Bs[lk + 0][lrow] = b4.x; Bs[lk + 1][lrow] = b4.y;
        Bs[lk + 2][lrow] = b4.z; Bs[lk + 3][lrow] = b4.w;
        __syncthreads();
#pragma unroll
        for (int kk = 0; kk < 8; ++kk) {
            float4 alo = *(const float4*)&As[kk][ty * 8];
            float4 ahi = *(const float4*)&As[kk][ty * 8 + 4];
            float4 blo = *(const float4*)&Bs[kk][tx * 8];
            float4 bhi = *(const float4*)&Bs[kk][tx * 8 + 4];
            float a[8] = {alo.x, alo.y, alo.z, alo.w, ahi.x, ahi.y, ahi.z, ahi.w};
            float b[8] = {blo.x, blo.y, blo.z, blo.w, bhi.x, bhi.y, bhi.z, bhi.w};
#pragma unroll
            for (int i = 0; i < 8; i++)
#pragma unroll
                for (int j = 0; j < 8; j++)
                    acc[i][j] = fmaf(a[i], b[j], acc[i][j]);
        }
    }

#pragma unroll
    for (int i = 0; i < 8; i++) {
        int row = m0 + ty * 8 + i;
        if (row >= M) continue;
#pragma unroll
        for (int j = 0; j < 8; j++) {
            int col = n0 + tx * 8 + j;
            if (col >= N) continue;
            float v = acc[i][j];
            if (EPI == 0) {
                C[(size_t)row * ldc + col] = v;
            } else if (EPI == 1) {
                atomicAdd(&C[(size_t)row * ldc + col], v);
            } else {
                float z = v + bias[col];
                float sp = (z > 0.f) ? (z + log1pf(__expf(-z))) : log1pf(__expf(z));
                C[(size_t)row * ldc + col] = sp;
            }
        }
    }
}

// causal depthwise conv (K=4, left pad 3) + bias + SiLU
// reads x-half of proj (cols 0..2047 of 4096-wide rows), writes x [B*L, 2048]
__global__ __launch_bounds__(256) void conv_silu_kernel(
    const float* __restrict__ proj, const float* __restrict__ conv_w,
    const float* __restrict__ conv_b, float* __restrict__ x)
{
    const int d = blockIdx.x * 256 + threadIdx.x;  // 0..2047
    const int l = blockIdx.y;
    const int b = blockIdx.z;
    const float w0 = conv_w[d * 4 + 0], w1 = conv_w[d * 4 + 1];
    const float w2 = conv_w[d * 4 + 2], w3 = conv_w[d * 4 + 3];
    const size_t base = (size_t)(b * L_) * 4096 + d;
    float s = conv_b[d];
    if (l >= 3) s += w0 * proj[base + (size_t)(l - 3) * 4096];
    if (l >= 2) s += w1 * proj[base + (size_t)(l - 2) * 4096];
    if (l >= 1) s += w2 * proj[base + (size_t)(l - 1) * 4096];
    s += w3 * proj[base + (size_t)l * 4096];
    x[(size_t)(b * L_ + l) * 2048 + d] = siluf(s);
}

// Selective scan. thread <-> (b, d, n): 16 lanes per d (n = lane&15).
// h[b,d,n] in a register, sequential over L with 1-step prefetch.
// Epilogue fused: y2 = (y + x*D) * silu(gate)
__global__ __launch_bounds__(256) void scan_kernel(
    const float* __restrict__ dt, const float* __restrict__ x,
    const float* __restrict__ sp, const float* __restrict__ A_log,
    const float* __restrict__ Dp, const float* __restrict__ proj,
    float* __restrict__ y2)
{
    const int tid = threadIdx.x;
    const int n = tid & 15;
    const int d = blockIdx.x * 16 + (tid >> 4);
    const int b = blockIdx.y;
    const float An = -__expf(A_log[d * 16 + n]);  // A = -exp(A_log)
    const float Dv = Dp[d];
    float h = 0.f;
    const size_t row = (size_t)b * L_;

    float dt_c = dt[row * 2048 + d];
    float x_c  = x[row * 2048 + d];
    float B_c  = sp[row * 96 + 64 + n];
    float C_c  = sp[row * 96 + 80 + n];
    float g_c  = proj[row * 4096 + 2048 + d];

    for (int l = 0; l < L_; ++l) {
        float dt_n = 0.f, x_n = 0.f, B_n = 0.f, C_n = 0.f, g_n = 0.f;
        if (l + 1 < L_) {
            const size_t r1 = row + l + 1;
            dt_n = dt[r1 * 2048 + d];
            x_n  = x[r1 * 2048 + d];
            B_n  = sp[r1 * 96 + 64 + n];
            C_n  = sp[r1 * 96 + 80 + n];
            g_n  = proj[r1 * 4096 + 2048 + d];
        }
        const float dA = __expf(dt_c * An);
        h = dA * h + dt_c * B_c * x_c;
        float p = h * C_c;
        p += __shfl_xor(p, 1);
        p += __shfl_xor(p, 2);
        p += __shfl_xor(p, 4);
        p += __shfl_xor(p, 8);
        if (n == 0) {
            const float yv = (p + x_c * Dv) * siluf(g_c);
            y2[(row + l) * 2048 + d] = yv;
        }
        dt_c = dt_n; x_c = x_n; B_c = B_n; C_c = C_n; g_c = g_n;
    }
}

extern "C" void kernel_launch(void* const* d_in, const int* in_sizes, int n_in,
                              void* d_out, int out_size, void* d_ws, size_t ws_size,
                              hipStream_t stream)
{
    const float* hs     = (const float*)d_in[0];
    const float* W_in   = (const float*)d_in[1];
    const float* conv_w = (const float*)d_in[2];
    const float* conv_b = (const float*)d_in[3];
    const float* W_x    = (const float*)d_in[4];
    const float* W_dt   = (const float*)d_in[5];
    const float* b_dt   = (const float*)d_in[6];
    const float* A_log  = (const float*)d_in[7];
    const float* Dp     = (const float*)d_in[8];
    const float* W_out  = (const float*)d_in[9];
    float* out = (float*)d_out;

    // workspace layout (floats): ~84.7 MB total
    float* ws    = (float*)d_ws;
    float* proj  = ws;                          // 2048*4096
    float* x     = proj + (size_t)2048 * 4096;  // 2048*2048
    float* ssm_p = x + (size_t)2048 * 2048;     // 2048*96
    float* dt    = ssm_p + (size_t)2048 * 96;   // 2048*2048
    float* y2    = dt + (size_t)2048 * 2048;    // 2048*2048

    const int M = B_ * L_;  // 2048

    // 1. proj = hs @ W_in^T : [2048,4096], K=1024
    gemm_nt<0><<<dim3(4096 / 128, M / 128, 1), 256, 0, stream>>>(
        hs, W_in, proj, M, 4096, 1024, 1024, 1024, 4096, 1024, nullptr);

    // 2. causal conv + SiLU -> x [2048,2048]
    conv_silu_kernel<<<dim3(D_ / 256, L_, B_), 256, 0, stream>>>(proj, conv_w, conv_b, x);

    // 3. ssm_p = x @ W_x^T : [2048,96], K=2048 split into 8 chunks of 256 (atomic)
    hipMemsetAsync(ssm_p, 0, (size_t)M * 96 * sizeof(float), stream);
    gemm_nt<1><<<dim3(1, M / 128, 8), 256, 0, stream>>>(
        x, W_x, ssm_p, M, 96, 2048, 2048, 2048, 96, 256, nullptr);

    // 4. dt = softplus(ssm_p[:, :64] @ W_dt^T + b_dt) : [2048,2048], K=64
    gemm_nt<2><<<dim3(2048 / 128, M / 128, 1), 256, 0, stream>>>(
        ssm_p, W_dt, dt, M, 2048, 64, 96, 64, 2048, 64, b_dt);

    // 5. scan + fused gating -> y2 [2048,2048]
    scan_kernel<<<dim3(D_ / 16, B_), 256, 0, stream>>>(dt, x, ssm_p, A_log, Dp, proj, y2);

    // 6. out = y2 @ W_out^T : [2048,1024], K=2048
    gemm_nt<0><<<dim3(1024 / 128, M / 128, 1), 256, 0, stream>>>(
        y2, W_out, out, M, 1024, 2048, 2048, 2048, 1024, 2048, nullptr);
}

// Round 2
// 601.916 us; speedup vs baseline: 1.8805x; 1.8805x over previous
//
#include <hip/hip_runtime.h>
#include <hip/hip_bf16.h>
#include <math.h>

#define B_ 2
#define L_ 1024
#define H_ 1024
#define D_ 2048
#define N_ 16
#define R_ 64
#define PF 16

typedef short short8 __attribute__((ext_vector_type(8)));
typedef float floatx4 __attribute__((ext_vector_type(4)));

__device__ __forceinline__ float siluf(float g) {
    return g / (1.0f + __expf(-g));
}

__device__ __forceinline__ unsigned short f2bf(float f) {
    unsigned int u = __float_as_uint(f);
    u = (u + 0x7fffu + ((u >> 16) & 1u)) >> 16;  // RNE
    return (unsigned short)u;
}

// ---------------- fp32 -> bf16 convert (vectorized) ----------------
__global__ __launch_bounds__(256) void cvt_bf16(
    const float* __restrict__ in, unsigned short* __restrict__ out, int n)
{
    int i = (blockIdx.x * 256 + threadIdx.x) * 4;
    if (i >= n) return;
    float4 v = *(const float4*)(in + i);
    ushort4 o;
    o.x = f2bf(v.x); o.y = f2bf(v.y); o.z = f2bf(v.z); o.w = f2bf(v.w);
    *(ushort4*)(out + i) = o;
}

// ---------------- bf16 MFMA GEMM: C[M,N] = A[M,K] @ B[N,K]^T ----------------
// 128x128 tile, BK=32, 256 threads (4 waves, 2x2 of 64x64), 16x16x32 MFMA.
// A, Bm are bf16 (raw ushort bits), C is fp32. M,N multiples of 128; K of 32.
__global__ __launch_bounds__(256) void gemm_bf16_nt(
    const unsigned short* __restrict__ A, const unsigned short* __restrict__ Bm,
    float* __restrict__ C, int K, int N)
{
    __shared__ unsigned short As[128 * 32];
    __shared__ unsigned short Bs[128 * 32];
    const int tid  = threadIdx.x;
    const int lane = tid & 63;
    const int wave = tid >> 6;
    const int wm = (wave >> 1) * 64;
    const int wn = (wave & 1) * 64;
    const int lr   = lane & 15;
    const int quad = lane >> 4;
    const int m0 = blockIdx.y * 128;
    const int n0 = blockIdx.x * 128;
    const int r0 = tid >> 2;            // staging row 0..63
    const int q0 = (tid & 3) * 8;       // k-chunk within row (8 bf16 = 16B)

    floatx4 acc[4][4];
#pragma unroll
    for (int mi = 0; mi < 4; ++mi)
#pragma unroll
        for (int ni = 0; ni < 4; ++ni)
            acc[mi][ni] = (floatx4){0.f, 0.f, 0.f, 0.f};

    const size_t a_base0 = (size_t)(m0 + r0) * K + q0;
    const size_t a_base1 = (size_t)(m0 + 64 + r0) * K + q0;
    const size_t b_base0 = (size_t)(n0 + r0) * K + q0;
    const size_t b_base1 = (size_t)(n0 + 64 + r0) * K + q0;
    const int lds_w = r0 * 32 + q0;

    for (int kt = 0; kt < K; kt += 32) {
        uint4 a0 = *(const uint4*)(A + a_base0 + kt);
        uint4 a1 = *(const uint4*)(A + a_base1 + kt);
        uint4 b0 = *(const uint4*)(Bm + b_base0 + kt);
        uint4 b1 = *(const uint4*)(Bm + b_base1 + kt);
        __syncthreads();
        *(uint4*)&As[lds_w]           = a0;
        *(uint4*)&As[lds_w + 64 * 32] = a1;
        *(uint4*)&Bs[lds_w]           = b0;
        *(uint4*)&Bs[lds_w + 64 * 32] = b1;
        __syncthreads();
        short8 af[4], bf[4];
#pragma unroll
        for (int mi = 0; mi < 4; ++mi)
            af[mi] = *(const short8*)&As[(wm + mi * 16 + lr) * 32 + quad * 8];
#pragma unroll
        for (int ni = 0; ni < 4; ++ni)
            bf[ni] = *(const short8*)&Bs[(wn + ni * 16 + lr) * 32 + quad * 8];
#pragma unroll
        for (int mi = 0; mi < 4; ++mi)
#pragma unroll
            for (int ni = 0; ni < 4; ++ni)
                acc[mi][ni] = __builtin_amdgcn_mfma_f32_16x16x32_bf16(
                    af[mi], bf[ni], acc[mi][ni], 0, 0, 0);
    }

#pragma unroll
    for (int mi = 0; mi < 4; ++mi)
#pragma unroll
        for (int ni = 0; ni < 4; ++ni) {
            const int rr = m0 + wm + mi * 16 + quad * 4;
            const int cc = n0 + wn + ni * 16 + lr;
#pragma unroll
            for (int r = 0; r < 4; ++r)
                C[(size_t)(rr + r) * N + cc] = acc[mi][ni][r];
        }
}

// ---------------- fp32 tile GEMM (kept for the two small GEMMs) ----------------
// C[M,N] = A[M,K] @ B[N,K]^T. EPI: 1 = atomicAdd (K-split), 2 = softplus(acc+bias)
template<int EPI>
__global__ __launch_bounds__(256) void gemm_nt(
    const float* __restrict__ A, const float* __restrict__ Bm, float* __restrict__ C,
    int M, int N, int K, int lda, int ldb, int ldc, int kChunk,
    const float* __restrict__ bias)
{
    __shared__ float As[8][132];
    __shared__ float Bs[8][132];
    const int tid = threadIdx.x;
    const int m0 = blockIdx.y * 128;
    const int n0 = blockIdx.x * 128;
    const int k0 = blockIdx.z * kChunk;
    const int kEnd = min(K, k0 + kChunk);
    const int tx = tid & 15;
    const int ty = tid >> 4;
    const int lrow = tid >> 1;
    const int lk = (tid & 1) * 4;

    float acc[8][8];
#pragma unroll
    for (int i = 0; i < 8; i++)
#pragma unroll
        for (int j = 0; j < 8; j++) acc[i][j] = 0.f;

    for (int kt = k0; kt < kEnd; kt += 8) {
        float4 a4 = *(const float4*)(A + (size_t)(m0 + lrow) * lda + kt + lk);
        float4 b4 = make_float4(0.f, 0.f, 0.f, 0.f);
        if (n0 + lrow < N)
            b4 = *(const float4*)(Bm + (size_t)(n0 + lrow) * ldb + kt + lk);
        __syncthreads();
        As[lk + 0][lrow] = a4.x; As[lk + 1][lrow] = a4.y;
        As[lk + 2][lrow] = a4.z; As[lk + 3][lrow] = a4.w;
        Bs[lk + 0][lrow] = b4.x; Bs[lk + 1][lrow] = b4.y;
        Bs[lk + 2][lrow] = b4.z; Bs[lk + 3][lrow] = b4.w;
        __syncthreads();
#pragma unroll
        for (int kk = 0; kk < 8; ++kk) {
            float4 alo = *(const float4*)&As[kk][ty * 8];
            float4 ahi = *(const float4*)&As[kk][ty * 8 + 4];
            float4 blo = *(const float4*)&Bs[kk][tx * 8];
            float4 bhi = *(const float4*)&Bs[kk][tx * 8 + 4];
            float a[8] = {alo.x, alo.y, alo.z, alo.w, ahi.x, ahi.y, ahi.z, ahi.w};
            float b[8] = {blo.x, blo.y, blo.z, blo.w, bhi.x, bhi.y, bhi.z, bhi.w};
#pragma unroll
            for (int i = 0; i < 8; i++)
#pragma unroll
                for (int j = 0; j < 8; j++)
                    acc[i][j] = fmaf(a[i], b[j], acc[i][j]);
        }
    }

#pragma unroll
    for (int i = 0; i < 8; i++) {
        int row = m0 + ty * 8 + i;
        if (row >= M) continue;
#pragma unroll
        for (int j = 0; j < 8; j++) {
            int col = n0 + tx * 8 + j;
            if (col >= N) continue;
            float v = acc[i][j];
            if (EPI == 1) {
                atomicAdd(&C[(size_t)row * ldc + col], v);
            } else {
                float z = v + bias[col];
                float sp = (z > 0.f) ? (z + log1pf(__expf(-z))) : log1pf(__expf(z));
                C[(size_t)row * ldc + col] = sp;
            }
        }
    }
}

// ---------------- causal depthwise conv (K=4) + bias + SiLU ----------------
__global__ __launch_bounds__(256) void conv_silu_kernel(
    const float* __restrict__ proj, const float* __restrict__ conv_w,
    const float* __restrict__ conv_b, float* __restrict__ x)
{
    const int d = blockIdx.x * 256 + threadIdx.x;
    const int l = blockIdx.y;
    const int b = blockIdx.z;
    const float w0 = conv_w[d * 4 + 0], w1 = conv_w[d * 4 + 1];
    const float w2 = conv_w[d * 4 + 2], w3 = conv_w[d * 4 + 3];
    const size_t base = (size_t)(b * L_) * 4096 + d;
    float s = conv_b[d];
    if (l >= 3) s += w0 * proj[base + (size_t)(l - 3) * 4096];
    if (l >= 2) s += w1 * proj[base + (size_t)(l - 2) * 4096];
    if (l >= 1) s += w2 * proj[base + (size_t)(l - 1) * 4096];
    s += w3 * proj[base + (size_t)l * 4096];
    x[(size_t)(b * L_ + l) * 2048 + d] = siluf(s);
}

// ---------------- selective scan, 16-deep prefetch, fused gating ----------------
// dt lives in proj[:, 0:2048], gate in proj[:, 2048:4096]. Writes y2 as bf16.
__global__ __launch_bounds__(256) void scan_kernel(
    const float* __restrict__ proj, const float* __restrict__ x,
    const float* __restrict__ sp, const float* __restrict__ A_log,
    const float* __restrict__ Dp, unsigned short* __restrict__ y2)
{
    const int tid = threadIdx.x;
    const int n = tid & 15;
    const int d = blockIdx.x * 16 + (tid >> 4);
    const int b = blockIdx.y;
    const float An = -__expf(A_log[d * 16 + n]);
    const float Dv = Dp[d];
    float h = 0.f;
    const size_t row = (size_t)b * L_;

    float dt_r[PF], x_r[PF], B_r[PF], C_r[PF], g_r[PF];
#pragma unroll
    for (int j = 0; j < PF; ++j) {
        const size_t r = row + j;
        dt_r[j] = proj[r * 4096 + d];
        g_r[j]  = proj[r * 4096 + 2048 + d];
        x_r[j]  = x[r * 2048 + d];
        B_r[j]  = sp[r * 96 + 64 + n];
        C_r[j]  = sp[r * 96 + 80 + n];
    }

    for (int lo = 0; lo < L_; lo += PF) {
#pragma unroll
        for (int j = 0; j < PF; ++j) {
            const float dtv = dt_r[j], xv = x_r[j], gv = g_r[j];
            const float Bv = B_r[j], Cv = C_r[j];
            // prefetch slot j for iteration lo+PF+j (issued early, used 16 iters later)
            {
                const int lp = min(lo + PF + j, L_ - 1);
                const size_t r = row + lp;
                dt_r[j] = proj[r * 4096 + d];
                g_r[j]  = proj[r * 4096 + 2048 + d];
                x_r[j]  = x[r * 2048 + d];
                B_r[j]  = sp[r * 96 + 64 + n];
                C_r[j]  = sp[r * 96 + 80 + n];
            }
            const float dA = __expf(dtv * An);
            h = fmaf(dA, h, dtv * Bv * xv);
            float p = h * Cv;
            p += __shfl_xor(p, 1);
            p += __shfl_xor(p, 2);
            p += __shfl_xor(p, 4);
            p += __shfl_xor(p, 8);
            if (n == 0) {
                const float yv = fmaf(xv, Dv, p) * siluf(gv);
                y2[(row + lo + j) * 2048 + d] = f2bf(yv);
            }
        }
    }
}

extern "C" void kernel_launch(void* const* d_in, const int* in_sizes, int n_in,
                              void* d_out, int out_size, void* d_ws, size_t ws_size,
                              hipStream_t stream)
{
    const float* hs     = (const float*)d_in[0];
    const float* conv_w = (const float*)d_in[2];
    const float* conv_b = (const float*)d_in[3];
    const float* W_x    = (const float*)d_in[4];
    const float* W_dt   = (const float*)d_in[5];
    const float* b_dt   = (const float*)d_in[6];
    const float* A_log  = (const float*)d_in[7];
    const float* Dp     = (const float*)d_in[8];
    const float* W_in   = (const float*)d_in[1];
    const float* W_out  = (const float*)d_in[9];
    float* out = (float*)d_out;

    // workspace layout: fp32 region then bf16 region (total ~72.75 MB)
    float* ws    = (float*)d_ws;
    float* proj  = ws;                              // 2048*4096 f32 (x-half reused as dt)
    float* x     = proj + (size_t)2048 * 4096;      // 2048*2048 f32
    float* ssm_p = x + (size_t)2048 * 2048;         // 2048*96 f32
    unsigned short* hs_bf    = (unsigned short*)(ssm_p + (size_t)2048 * 96);
    unsigned short* W_in_bf  = hs_bf + (size_t)2048 * 1024;      // 4096*1024
    unsigned short* W_out_bf = W_in_bf + (size_t)4096 * 1024;    // 1024*2048
    unsigned short* y2_bf    = W_out_bf + (size_t)1024 * 2048;   // 2048*2048

    const int M = B_ * L_;  // 2048

    // 0. fp32 -> bf16 converts
    cvt_bf16<<<(2048 * 1024) / 1024, 256, 0, stream>>>(hs, hs_bf, 2048 * 1024);
    cvt_bf16<<<(4096 * 1024) / 1024, 256, 0, stream>>>(W_in, W_in_bf, 4096 * 1024);
    cvt_bf16<<<(1024 * 2048) / 1024, 256, 0, stream>>>(W_out, W_out_bf, 1024 * 2048);

    // 1. proj = hs @ W_in^T : [2048,4096], K=1024 (bf16 MFMA)
    gemm_bf16_nt<<<dim3(4096 / 128, M / 128), 256, 0, stream>>>(
        hs_bf, W_in_bf, proj, 1024, 4096);

    // 2. causal conv + SiLU -> x [2048,2048]
    conv_silu_kernel<<<dim3(D_ / 256, L_, B_), 256, 0, stream>>>(proj, conv_w, conv_b, x);

    // 3. ssm_p = x @ W_x^T : [2048,96], K=2048 split into 8 chunks (atomic)
    hipMemsetAsync(ssm_p, 0, (size_t)M * 96 * sizeof(float), stream);
    gemm_nt<1><<<dim3(1, M / 128, 8), 256, 0, stream>>>(
        x, W_x, ssm_p, M, 96, 2048, 2048, 2048, 96, 256, nullptr);

    // 4. dt = softplus(ssm_p[:, :64] @ W_dt^T + b_dt) -> proj[:, 0:2048] (ldc=4096)
    gemm_nt<2><<<dim3(2048 / 128, M / 128, 1), 256, 0, stream>>>(
        ssm_p, W_dt, proj, M, 2048, 64, 96, 64, 4096, 64, b_dt);

    // 5. scan + fused gating -> y2 (bf16)
    scan_kernel<<<dim3(D_ / 16, B_), 256, 0, stream>>>(proj, x, ssm_p, A_log, Dp, y2_bf);

    // 6. out = y2 @ W_out^T : [2048,1024], K=2048 (bf16 MFMA)
    gemm_bf16_nt<<<dim3(1024 / 128, M / 128), 256, 0, stream>>>(
        y2_bf, W_out_bf, out, 2048, 1024);
}

// Round 3
// 492.073 us; speedup vs baseline: 2.3003x; 1.2232x over previous
//
#include <hip/hip_runtime.h>
#include <hip/hip_bf16.h>
#include <math.h>

#define B_ 2
#define L_ 1024
#define H_ 1024
#define D_ 2048
#define N_ 16
#define R_ 64
#define NCHUNK 8
#define CLEN 128   // L_ / NCHUNK

typedef short short8 __attribute__((ext_vector_type(8)));
typedef float floatx4 __attribute__((ext_vector_type(4)));

__device__ __forceinline__ float siluf(float g) {
    return g / (1.0f + __expf(-g));
}

__device__ __forceinline__ unsigned short f2bf(float f) {
    unsigned int u = __float_as_uint(f);
    u = (u + 0x7fffu + ((u >> 16) & 1u)) >> 16;  // RNE
    return (unsigned short)u;
}

// async global->LDS, 16B per lane; lds base must be wave-uniform
__device__ __forceinline__ void gl2lds(const unsigned short* g, unsigned short* l) {
    __builtin_amdgcn_global_load_lds(
        (const __attribute__((address_space(1))) unsigned int*)g,
        (__attribute__((address_space(3))) unsigned int*)l, 16, 0, 0);
}

// ---------------- fp32 -> bf16 convert (vectorized) ----------------
__global__ __launch_bounds__(256) void cvt_bf16(
    const float* __restrict__ in, unsigned short* __restrict__ out, int n)
{
    int i = (blockIdx.x * 256 + threadIdx.x) * 4;
    if (i >= n) return;
    float4 v = *(const float4*)(in + i);
    ushort4 o;
    o.x = f2bf(v.x); o.y = f2bf(v.y); o.z = f2bf(v.z); o.w = f2bf(v.w);
    *(ushort4*)(out + i) = o;
}

// ---------------- bf16 MFMA GEMM: C[M,N] = A[M,K] @ B[N,K]^T ----------------
// 128x128 tile, BK=32, 256 threads (4 waves, 2x2 of 64x64), 16x16x32 MFMA,
// global_load_lds width-16 staging (m97 structure).
// EPI: 0 = plain store, 1 = atomicAdd (K-split). Col guard at Ncols; B-row clamp at nMax.
template<int EPI>
__global__ __launch_bounds__(256) void gemm_bf16_nt(
    const unsigned short* __restrict__ A, const unsigned short* __restrict__ Bm,
    float* __restrict__ C, int K, int Ncols, int ldc, int kChunk, int nMax)
{
    __shared__ unsigned short As[128 * 32];
    __shared__ unsigned short Bs[128 * 32];
    const int tid  = threadIdx.x;
    const int lane = tid & 63;
    const int wave = tid >> 6;
    const int wm = (wave >> 1) * 64;
    const int wn = (wave & 1) * 64;
    const int lr   = lane & 15;
    const int quad = lane >> 4;
    const int m0 = blockIdx.y * 128;
    const int n0 = blockIdx.x * 128;
    const int k0 = blockIdx.z * kChunk;

    // staging geometry: wave w, call c in {0,1} covers rows w*32+c*16+(lane>>2),
    // 16B chunk (lane&3)*8 within the 32-elem row. LDS dest = uniform base + lane*16B.
    const int srow = wave * 32 + (lane >> 2);
    const int sq   = (lane & 3) * 8;
    unsigned short* AsB0 = &As[(wave * 32) * 32];
    unsigned short* AsB1 = &As[(wave * 32 + 16) * 32];
    unsigned short* BsB0 = &Bs[(wave * 32) * 32];
    unsigned short* BsB1 = &Bs[(wave * 32 + 16) * 32];
    const size_t aoff0 = (size_t)(m0 + srow) * K + sq;
    const size_t aoff1 = (size_t)(m0 + srow + 16) * K + sq;
    const size_t boff0 = (size_t)min(n0 + srow, nMax - 1) * K + sq;
    const size_t boff1 = (size_t)min(n0 + srow + 16, nMax - 1) * K + sq;

    floatx4 acc[4][4];
#pragma unroll
    for (int mi = 0; mi < 4; ++mi)
#pragma unroll
        for (int ni = 0; ni < 4; ++ni)
            acc[mi][ni] = (floatx4){0.f, 0.f, 0.f, 0.f};

    for (int kt = k0; kt < k0 + kChunk; kt += 32) {
        __syncthreads();
        gl2lds(A + aoff0 + kt, AsB0);
        gl2lds(A + aoff1 + kt, AsB1);
        gl2lds(Bm + boff0 + kt, BsB0);
        gl2lds(Bm + boff1 + kt, BsB1);
        __syncthreads();
        short8 af[4], bf[4];
#pragma unroll
        for (int mi = 0; mi < 4; ++mi)
            af[mi] = *(const short8*)&As[(wm + mi * 16 + lr) * 32 + quad * 8];
#pragma unroll
        for (int ni = 0; ni < 4; ++ni)
            bf[ni] = *(const short8*)&Bs[(wn + ni * 16 + lr) * 32 + quad * 8];
#pragma unroll
        for (int mi = 0; mi < 4; ++mi)
#pragma unroll
            for (int ni = 0; ni < 4; ++ni)
                acc[mi][ni] = __builtin_amdgcn_mfma_f32_16x16x32_bf16(
                    af[mi], bf[ni], acc[mi][ni], 0, 0, 0);
    }

#pragma unroll
    for (int mi = 0; mi < 4; ++mi)
#pragma unroll
        for (int ni = 0; ni < 4; ++ni) {
            const int rr = m0 + wm + mi * 16 + quad * 4;
            const int cc = n0 + wn + ni * 16 + lr;
            if (cc >= Ncols) continue;
#pragma unroll
            for (int r = 0; r < 4; ++r) {
                if (EPI == 0)
                    C[(size_t)(rr + r) * ldc + cc] = acc[mi][ni][r];
                else
                    atomicAdd(&C[(size_t)(rr + r) * ldc + cc], acc[mi][ni][r]);
            }
        }
}

// ---------------- fp32 tile GEMM (dt path only): softplus(A@B^T + bias) ----------------
__global__ __launch_bounds__(256) void gemm_nt_softplus(
    const float* __restrict__ A, const float* __restrict__ Bm, float* __restrict__ C,
    int M, int N, int K, int lda, int ldb, int ldc, const float* __restrict__ bias)
{
    __shared__ float As[8][132];
    __shared__ float Bs[8][132];
    const int tid = threadIdx.x;
    const int m0 = blockIdx.y * 128;
    const int n0 = blockIdx.x * 128;
    const int tx = tid & 15;
    const int ty = tid >> 4;
    const int lrow = tid >> 1;
    const int lk = (tid & 1) * 4;

    float acc[8][8];
#pragma unroll
    for (int i = 0; i < 8; i++)
#pragma unroll
        for (int j = 0; j < 8; j++) acc[i][j] = 0.f;

    for (int kt = 0; kt < K; kt += 8) {
        float4 a4 = *(const float4*)(A + (size_t)(m0 + lrow) * lda + kt + lk);
        float4 b4 = *(const float4*)(Bm + (size_t)(n0 + lrow) * ldb + kt + lk);
        __syncthreads();
        As[lk + 0][lrow] = a4.x; As[lk + 1][lrow] = a4.y;
        As[lk + 2][lrow] = a4.z; As[lk + 3][lrow] = a4.w;
        Bs[lk + 0][lrow] = b4.x; Bs[lk + 1][lrow] = b4.y;
        Bs[lk + 2][lrow] = b4.z; Bs[lk + 3][lrow] = b4.w;
        __syncthreads();
#pragma unroll
        for (int kk = 0; kk < 8; ++kk) {
            float4 alo = *(const float4*)&As[kk][ty * 8];
            float4 ahi = *(const float4*)&As[kk][ty * 8 + 4];
            float4 blo = *(const float4*)&Bs[kk][tx * 8];
            float4 bhi = *(const float4*)&Bs[kk][tx * 8 + 4];
            float a[8] = {alo.x, alo.y, alo.z, alo.w, ahi.x, ahi.y, ahi.z, ahi.w};
            float b[8] = {blo.x, blo.y, blo.z, blo.w, bhi.x, bhi.y, bhi.z, bhi.w};
#pragma unroll
            for (int i = 0; i < 8; i++)
#pragma unroll
                for (int j = 0; j < 8; j++)
                    acc[i][j] = fmaf(a[i], b[j], acc[i][j]);
        }
    }

#pragma unroll
    for (int i = 0; i < 8; i++) {
        int row = m0 + ty * 8 + i;
#pragma unroll
        for (int j = 0; j < 8; j++) {
            int col = n0 + tx * 8 + j;
            float z = acc[i][j] + bias[col];
            float sp = (z > 0.f) ? (z + log1pf(__expf(-z))) : log1pf(__expf(z));
            C[(size_t)row * ldc + col] = sp;
        }
    }
}

// ---------------- causal depthwise conv (K=4) + bias + SiLU ----------------
// writes x fp32 (for scan) and x_bf bf16 (for ssm_p MFMA GEMM)
__global__ __launch_bounds__(256) void conv_silu_kernel(
    const float* __restrict__ proj, const float* __restrict__ conv_w,
    const float* __restrict__ conv_b, float* __restrict__ x,
    unsigned short* __restrict__ x_bf)
{
    const int d = blockIdx.x * 256 + threadIdx.x;
    const int l = blockIdx.y;
    const int b = blockIdx.z;
    const float w0 = conv_w[d * 4 + 0], w1 = conv_w[d * 4 + 1];
    const float w2 = conv_w[d * 4 + 2], w3 = conv_w[d * 4 + 3];
    const size_t base = (size_t)(b * L_) * 4096 + d;
    float s = conv_b[d];
    if (l >= 3) s += w0 * proj[base + (size_t)(l - 3) * 4096];
    if (l >= 2) s += w1 * proj[base + (size_t)(l - 2) * 4096];
    if (l >= 1) s += w2 * proj[base + (size_t)(l - 1) * 4096];
    s += w3 * proj[base + (size_t)l * 4096];
    const float v = siluf(s);
    const size_t o = (size_t)(b * L_ + l) * 2048 + d;
    x[o] = v;
    x_bf[o] = f2bf(v);
}

// ---------------- chunked selective scan (two-pass) + fused gating ----------------
// Linear recurrence h_l = dA_l h_{l-1} + u_l split into NCHUNK chunks:
// pass 1: per-chunk P = prod dA, H = scan from 0. Combine serially (exact).
// pass 2: rescan with true h_in, reduce over n (16-lane shfl), emit y2 bf16.
// Block: 256 thr = 2 d's x 8 chunks x 16 n. Grid: (D/2, B) = 2048 blocks.
__global__ __launch_bounds__(256) void scan_kernel(
    const float* __restrict__ proj, const float* __restrict__ x,
    const float* __restrict__ sp, const float* __restrict__ A_log,
    const float* __restrict__ Dp, unsigned short* __restrict__ y2)
{
    const int tid = threadIdx.x;
    const int n  = tid & 15;
    const int ck = (tid >> 4) & 7;
    const int dl = tid >> 7;
    const int d = blockIdx.x * 2 + dl;
    const int b = blockIdx.y;
    const float An = -__expf(A_log[d * 16 + n]);
    const size_t row = (size_t)b * L_;
    const int l0 = ck * CLEN;

    __shared__ float Pc[2][NCHUNK][16];
    __shared__ float Hc[2][NCHUNK][16];
    __shared__ float Hin[2][NCHUNK][16];

    // pass 1: chunk-local scan from zero
    float P = 1.f, h = 0.f;
#pragma unroll 8
    for (int l = l0; l < l0 + CLEN; ++l) {
        const size_t r = row + l;
        const float dtv = proj[r * 4096 + d];
        const float xv  = x[r * 2048 + d];
        const float Bv  = sp[r * 96 + 64 + n];
        const float dA = __expf(dtv * An);
        P *= dA;
        h = fmaf(dA, h, dtv * Bv * xv);
    }
    Pc[dl][ck][n] = P;
    Hc[dl][ck][n] = h;
    __syncthreads();

    // combine: one thread per (dl, n), serial over the 8 chunks
    if (tid < 32) {
        const int dd = tid >> 4, nn = tid & 15;
        float hin = 0.f;
#pragma unroll
        for (int c = 0; c < NCHUNK; ++c) {
            Hin[dd][c][nn] = hin;
            hin = fmaf(Pc[dd][c][nn], hin, Hc[dd][c][nn]);
        }
    }
    __syncthreads();

    // pass 2: rescan with correct h_in, produce outputs
    h = Hin[dl][ck][n];
    const float Dv = Dp[d];
#pragma unroll 8
    for (int l = l0; l < l0 + CLEN; ++l) {
        const size_t r = row + l;
        const float dtv = proj[r * 4096 + d];
        const float gv  = proj[r * 4096 + 2048 + d];
        const float xv  = x[r * 2048 + d];
        const float Bv  = sp[r * 96 + 64 + n];
        const float Cv  = sp[r * 96 + 80 + n];
        const float dA = __expf(dtv * An);
        h = fmaf(dA, h, dtv * Bv * xv);
        float p = h * Cv;
        p += __shfl_xor(p, 1);
        p += __shfl_xor(p, 2);
        p += __shfl_xor(p, 4);
        p += __shfl_xor(p, 8);
        if (n == 0)
            y2[r * 2048 + d] = f2bf(fmaf(xv, Dv, p) * siluf(gv));
    }
}

extern "C" void kernel_launch(void* const* d_in, const int* in_sizes, int n_in,
                              void* d_out, int out_size, void* d_ws, size_t ws_size,
                              hipStream_t stream)
{
    const float* hs     = (const float*)d_in[0];
    const float* W_in   = (const float*)d_in[1];
    const float* conv_w = (const float*)d_in[2];
    const float* conv_b = (const float*)d_in[3];
    const float* W_x    = (const float*)d_in[4];
    const float* W_dt   = (const float*)d_in[5];
    const float* b_dt   = (const float*)d_in[6];
    const float* A_log  = (const float*)d_in[7];
    const float* Dp     = (const float*)d_in[8];
    const float* W_out  = (const float*)d_in[9];
    float* out = (float*)d_out;

    // workspace layout (~81 MB)
    float* ws    = (float*)d_ws;
    float* proj  = ws;                              // 2048*4096 f32 (x-half reused as dt)
    float* x     = proj + (size_t)2048 * 4096;      // 2048*2048 f32
    float* ssm_p = x + (size_t)2048 * 2048;         // 2048*96 f32
    unsigned short* hs_bf    = (unsigned short*)(ssm_p + (size_t)2048 * 96);
    unsigned short* W_in_bf  = hs_bf + (size_t)2048 * 1024;      // 4096*1024
    unsigned short* W_out_bf = W_in_bf + (size_t)4096 * 1024;    // 1024*2048
    unsigned short* y2_bf    = W_out_bf + (size_t)1024 * 2048;   // 2048*2048
    unsigned short* x_bf     = y2_bf + (size_t)2048 * 2048;      // 2048*2048
    unsigned short* W_x_bf   = x_bf + (size_t)2048 * 2048;       // 96*2048

    const int M = B_ * L_;  // 2048

    // 0. fp32 -> bf16 converts
    cvt_bf16<<<(2048 * 1024) / 1024, 256, 0, stream>>>(hs, hs_bf, 2048 * 1024);
    cvt_bf16<<<(4096 * 1024) / 1024, 256, 0, stream>>>(W_in, W_in_bf, 4096 * 1024);
    cvt_bf16<<<(1024 * 2048) / 1024, 256, 0, stream>>>(W_out, W_out_bf, 1024 * 2048);
    cvt_bf16<<<(96 * 2048) / 1024, 256, 0, stream>>>(W_x, W_x_bf, 96 * 2048);

    // 1. proj = hs @ W_in^T : [2048,4096], K=1024 (bf16 MFMA, lds-staged)
    gemm_bf16_nt<0><<<dim3(4096 / 128, M / 128, 1), 256, 0, stream>>>(
        hs_bf, W_in_bf, proj, 1024, 4096, 4096, 1024, 4096);

    // 2. causal conv + SiLU -> x fp32 + x_bf
    conv_silu_kernel<<<dim3(D_ / 256, L_, B_), 256, 0, stream>>>(
        proj, conv_w, conv_b, x, x_bf);

    // 3. ssm_p = x @ W_x^T : [2048,96], K=2048, K-split 8 (bf16 MFMA, atomic fp32)
    hipMemsetAsync(ssm_p, 0, (size_t)M * 96 * sizeof(float), stream);
    gemm_bf16_nt<1><<<dim3(1, M / 128, 8), 256, 0, stream>>>(
        x_bf, W_x_bf, ssm_p, 2048, 96, 96, 256, 96);

    // 4. dt = softplus(ssm_p[:, :64] @ W_dt^T + b_dt) -> proj[:, 0:2048] (ldc=4096)
    gemm_nt_softplus<<<dim3(2048 / 128, M / 128, 1), 256, 0, stream>>>(
        ssm_p, W_dt, proj, M, 2048, 64, 96, 64, 4096, b_dt);

    // 5. chunked scan + fused gating -> y2 (bf16)
    scan_kernel<<<dim3(D_ / 2, B_), 256, 0, stream>>>(proj, x, ssm_p, A_log, Dp, y2_bf);

    // 6. out = y2 @ W_out^T : [2048,1024], K=2048 (bf16 MFMA, lds-staged)
    gemm_bf16_nt<0><<<dim3(1024 / 128, M / 128, 1), 256, 0, stream>>>(
        y2_bf, W_out_bf, out, 2048, 1024, 1024, 2048, 1024);
}

// Round 4
// 352.508 us; speedup vs baseline: 3.2110x; 1.3959x over previous
//
#include <hip/hip_runtime.h>
#include <hip/hip_bf16.h>
#include <math.h>

#define B_ 2
#define L_ 1024
#define H_ 1024
#define D_ 2048
#define N_ 16
#define R_ 64
#define NCHUNK 8
#define CLEN 128   // L_ / NCHUNK

typedef short short8 __attribute__((ext_vector_type(8)));
typedef float floatx4 __attribute__((ext_vector_type(4)));

__device__ __forceinline__ float siluf(float g) {
    return g / (1.0f + __expf(-g));
}

__device__ __forceinline__ unsigned short f2bf(float f) {
    unsigned int u = __float_as_uint(f);
    u = (u + 0x7fffu + ((u >> 16) & 1u)) >> 16;  // RNE
    return (unsigned short)u;
}

// async global->LDS, 16B per lane; lds base must be wave-uniform
__device__ __forceinline__ void gl2lds(const unsigned short* g, unsigned short* l) {
    __builtin_amdgcn_global_load_lds(
        (const __attribute__((address_space(1))) unsigned int*)g,
        (__attribute__((address_space(3))) unsigned int*)l, 16, 0, 0);
}

// ---------------- fp32 -> bf16 convert (vectorized) ----------------
__global__ __launch_bounds__(256) void cvt_bf16(
    const float* __restrict__ in, unsigned short* __restrict__ out, int n)
{
    int i = (blockIdx.x * 256 + threadIdx.x) * 4;
    if (i >= n) return;
    float4 v = *(const float4*)(in + i);
    ushort4 o;
    o.x = f2bf(v.x); o.y = f2bf(v.y); o.z = f2bf(v.z); o.w = f2bf(v.w);
    *(ushort4*)(out + i) = o;
}

// ---------------- bf16 MFMA GEMM: C = A[M,K] @ B[N,K]^T ----------------
// 128x128 tile, BK=32, 256 threads (4 waves, 2x2 of 64x64), 16x16x32 MFMA,
// global_load_lds width-16 staging.
// EPI: 0 = plain store C[m][n], 1 = atomicAdd C[m][n] (K-split),
//      2 = transposed store C[n][m] (ldc = stride of the n-major output)
template<int EPI>
__global__ __launch_bounds__(256) void gemm_bf16_nt(
    const unsigned short* __restrict__ A, const unsigned short* __restrict__ Bm,
    float* __restrict__ C, int K, int Ncols, int ldc, int kChunk, int nMax)
{
    __shared__ unsigned short As[128 * 32];
    __shared__ unsigned short Bs[128 * 32];
    const int tid  = threadIdx.x;
    const int lane = tid & 63;
    const int wave = tid >> 6;
    const int wm = (wave >> 1) * 64;
    const int wn = (wave & 1) * 64;
    const int lr   = lane & 15;
    const int quad = lane >> 4;
    const int m0 = blockIdx.y * 128;
    const int n0 = blockIdx.x * 128;
    const int k0 = blockIdx.z * kChunk;

    const int srow = wave * 32 + (lane >> 2);
    const int sq   = (lane & 3) * 8;
    unsigned short* AsB0 = &As[(wave * 32) * 32];
    unsigned short* AsB1 = &As[(wave * 32 + 16) * 32];
    unsigned short* BsB0 = &Bs[(wave * 32) * 32];
    unsigned short* BsB1 = &Bs[(wave * 32 + 16) * 32];
    const size_t aoff0 = (size_t)(m0 + srow) * K + sq;
    const size_t aoff1 = (size_t)(m0 + srow + 16) * K + sq;
    const size_t boff0 = (size_t)min(n0 + srow, nMax - 1) * K + sq;
    const size_t boff1 = (size_t)min(n0 + srow + 16, nMax - 1) * K + sq;

    floatx4 acc[4][4];
#pragma unroll
    for (int mi = 0; mi < 4; ++mi)
#pragma unroll
        for (int ni = 0; ni < 4; ++ni)
            acc[mi][ni] = (floatx4){0.f, 0.f, 0.f, 0.f};

    for (int kt = k0; kt < k0 + kChunk; kt += 32) {
        __syncthreads();
        gl2lds(A + aoff0 + kt, AsB0);
        gl2lds(A + aoff1 + kt, AsB1);
        gl2lds(Bm + boff0 + kt, BsB0);
        gl2lds(Bm + boff1 + kt, BsB1);
        __syncthreads();
        short8 af[4], bf[4];
#pragma unroll
        for (int mi = 0; mi < 4; ++mi)
            af[mi] = *(const short8*)&As[(wm + mi * 16 + lr) * 32 + quad * 8];
#pragma unroll
        for (int ni = 0; ni < 4; ++ni)
            bf[ni] = *(const short8*)&Bs[(wn + ni * 16 + lr) * 32 + quad * 8];
#pragma unroll
        for (int mi = 0; mi < 4; ++mi)
#pragma unroll
            for (int ni = 0; ni < 4; ++ni)
                acc[mi][ni] = __builtin_amdgcn_mfma_f32_16x16x32_bf16(
                    af[mi], bf[ni], acc[mi][ni], 0, 0, 0);
    }

#pragma unroll
    for (int mi = 0; mi < 4; ++mi)
#pragma unroll
        for (int ni = 0; ni < 4; ++ni) {
            const int rr = m0 + wm + mi * 16 + quad * 4;
            const int cc = n0 + wn + ni * 16 + lr;
            if (cc >= Ncols) continue;
            if (EPI == 2) {
                float4 v = make_float4(acc[mi][ni][0], acc[mi][ni][1],
                                       acc[mi][ni][2], acc[mi][ni][3]);
                *(float4*)&C[(size_t)cc * ldc + rr] = v;
            } else {
#pragma unroll
                for (int r = 0; r < 4; ++r) {
                    if (EPI == 0)
                        C[(size_t)(rr + r) * ldc + cc] = acc[mi][ni][r];
                    else
                        atomicAdd(&C[(size_t)(rr + r) * ldc + cc], acc[mi][ni][r]);
                }
            }
        }
}

// ---------------- fp32 NT GEMM: C[i][j] = softplus(A[i,:K]·B[j,:K] + bias[i]) ----
// used for dtT = softplus(W_dt @ dt_lr^T + b_dt): A=W_dt (2048x64), B=sp (ldb=96)
__global__ __launch_bounds__(256) void gemm_nt_softplus(
    const float* __restrict__ A, const float* __restrict__ Bm, float* __restrict__ C,
    int K, int lda, int ldb, int ldc, const float* __restrict__ bias)
{
    __shared__ float As[8][132];
    __shared__ float Bs[8][132];
    const int tid = threadIdx.x;
    const int m0 = blockIdx.y * 128;
    const int n0 = blockIdx.x * 128;
    const int tx = tid & 15;
    const int ty = tid >> 4;
    const int lrow = tid >> 1;
    const int lk = (tid & 1) * 4;

    float acc[8][8];
#pragma unroll
    for (int i = 0; i < 8; i++)
#pragma unroll
        for (int j = 0; j < 8; j++) acc[i][j] = 0.f;

    for (int kt = 0; kt < K; kt += 8) {
        float4 a4 = *(const float4*)(A + (size_t)(m0 + lrow) * lda + kt + lk);
        float4 b4 = *(const float4*)(Bm + (size_t)(n0 + lrow) * ldb + kt + lk);
        __syncthreads();
        As[lk + 0][lrow] = a4.x; As[lk + 1][lrow] = a4.y;
        As[lk + 2][lrow] = a4.z; As[lk + 3][lrow] = a4.w;
        Bs[lk + 0][lrow] = b4.x; Bs[lk + 1][lrow] = b4.y;
        Bs[lk + 2][lrow] = b4.z; Bs[lk + 3][lrow] = b4.w;
        __syncthreads();
#pragma unroll
        for (int kk = 0; kk < 8; ++kk) {
            float4 alo = *(const float4*)&As[kk][ty * 8];
            float4 ahi = *(const float4*)&As[kk][ty * 8 + 4];
            float4 blo = *(const float4*)&Bs[kk][tx * 8];
            float4 bhi = *(const float4*)&Bs[kk][tx * 8 + 4];
            float a[8] = {alo.x, alo.y, alo.z, alo.w, ahi.x, ahi.y, ahi.z, ahi.w};
            float b[8] = {blo.x, blo.y, blo.z, blo.w, bhi.x, bhi.y, bhi.z, bhi.w};
#pragma unroll
            for (int i = 0; i < 8; i++)
#pragma unroll
                for (int j = 0; j < 8; j++)
                    acc[i][j] = fmaf(a[i], b[j], acc[i][j]);
        }
    }

#pragma unroll
    for (int i = 0; i < 8; i++) {
        int row = m0 + ty * 8 + i;
        float bv = bias[row];
#pragma unroll
        for (int j = 0; j < 8; j++) {
            int col = n0 + tx * 8 + j;
            float z = acc[i][j] + bv;
            float sp = (z > 0.f) ? (z + log1pf(__expf(-z))) : log1pf(__expf(z));
            C[(size_t)row * ldc + col] = sp;
        }
    }
}

// ---------------- causal depthwise conv (K=4) + bias + SiLU, d-major ----------------
// reads projT[d][m] rows (contiguous), writes xT[d][m] fp32 + x_bf[m][d] bf16 (LDS transpose)
__global__ __launch_bounds__(256) void conv_silu_kernel(
    const float* __restrict__ projT, const float* __restrict__ conv_w,
    const float* __restrict__ conv_b, float* __restrict__ xT,
    unsigned short* __restrict__ x_bf)
{
    __shared__ unsigned short tile[64][72];
    const int t = threadIdx.x;
    const int d0 = blockIdx.x * 64;
    const int lt0 = blockIdx.y * 64;
    const int b = blockIdx.z;
    const int dl = t & 63;
    const int seg = t >> 6;
    const int d = d0 + dl;
    const int l0 = lt0 + seg * 16;
    const float* row = projT + (size_t)d * 2048 + b * 1024;
    const float w0 = conv_w[d * 4 + 0], w1 = conv_w[d * 4 + 1];
    const float w2 = conv_w[d * 4 + 2], w3 = conv_w[d * 4 + 3];
    const float bias = conv_b[d];

    float p[19];
    p[0] = (l0 >= 3) ? row[l0 - 3] : 0.f;
    p[1] = (l0 >= 2) ? row[l0 - 2] : 0.f;
    p[2] = (l0 >= 1) ? row[l0 - 1] : 0.f;
#pragma unroll
    for (int j = 0; j < 16; j += 4) {
        float4 q = *(const float4*)(row + l0 + j);
        p[3 + j] = q.x; p[4 + j] = q.y; p[5 + j] = q.z; p[6 + j] = q.w;
    }
    float v[16];
#pragma unroll
    for (int j = 0; j < 16; ++j)
        v[j] = siluf(bias + w0 * p[j] + w1 * p[j + 1] + w2 * p[j + 2] + w3 * p[j + 3]);

    float* xrow = xT + (size_t)d * 2048 + b * 1024 + l0;
#pragma unroll
    for (int j = 0; j < 16; j += 4)
        *(float4*)(xrow + j) = make_float4(v[j], v[j + 1], v[j + 2], v[j + 3]);

#pragma unroll
    for (int j = 0; j < 16; ++j)
        tile[seg * 16 + j][dl] = f2bf(v[j]);
    __syncthreads();

    const int ml = t >> 2;
    const int c = t & 3;
    short8 s0 = *(const short8*)&tile[ml][c * 16];
    short8 s1 = *(const short8*)&tile[ml][c * 16 + 8];
    unsigned short* dst = x_bf + (size_t)(b * 1024 + lt0 + ml) * 2048 + d0 + c * 16;
    *(short8*)dst = s0;
    *(short8*)(dst + 8) = s1;
}

// ---------------- bf16 tiled transpose: yT[d][m] -> y[m][d] ----------------
__global__ __launch_bounds__(256) void transpose_bf16(
    const unsigned short* __restrict__ in, unsigned short* __restrict__ out)
{
    __shared__ unsigned short tile[64][72];
    const int t = threadIdx.x;
    const int d0 = blockIdx.x * 64;
    const int m0 = blockIdx.y * 64;
    {
        const int dl = t >> 2, c = t & 3;
        const unsigned short* src = in + (size_t)(d0 + dl) * 2048 + m0 + c * 16;
        *(short8*)&tile[dl][c * 16]     = *(const short8*)src;
        *(short8*)&tile[dl][c * 16 + 8] = *(const short8*)(src + 8);
    }
    __syncthreads();
    {
        const int ml = t >> 2, c = t & 3;
        unsigned short v[16];
#pragma unroll
        for (int j = 0; j < 16; ++j)
            v[j] = tile[c * 16 + j][ml];
        unsigned short* dst = out + (size_t)(m0 + ml) * 2048 + d0 + c * 16;
        *(short8*)dst = *(short8*)&v[0];
        *(short8*)(dst + 8) = *(short8*)&v[8];
    }
}

// ---------------- chunked selective scan (two-pass, d-major) + fused gating ----------
// Inputs: dtT[d][m], xT[d][m], gate = projT rows 2048.., sp[m][96] (B,C small).
// Pass 1 caches dt/x chunks in LDS; pass 2 reads LDS + gate, writes yT[d][m] bf16.
// Block: 256 thr = 2 d x 8 chunks x 16 n. Grid: (D/2, B).
__global__ __launch_bounds__(256) void scan_kernel(
    const float* __restrict__ dtT, const float* __restrict__ xT,
    const float* __restrict__ projT, const float* __restrict__ sp,
    const float* __restrict__ A_log, const float* __restrict__ Dp,
    unsigned short* __restrict__ yT)
{
    __shared__ float sdt[2][NCHUNK][132];
    __shared__ float sx[2][NCHUNK][132];
    __shared__ float Pc[2][NCHUNK][16];
    __shared__ float Hc[2][NCHUNK][16];
    __shared__ float Hin[2][NCHUNK][16];

    const int tid = threadIdx.x;
    const int n  = tid & 15;
    const int ck = (tid >> 4) & 7;
    const int dl = tid >> 7;
    const int d = blockIdx.x * 2 + dl;
    const int b = blockIdx.y;
    const float An = -__expf(A_log[d * 16 + n]);
    const int mb = b * 1024 + ck * CLEN;           // m base for this chunk

    const float* pdt = dtT + (size_t)d * 2048 + mb;
    const float* px  = xT + (size_t)d * 2048 + mb;
    const float* pg  = projT + (size_t)(2048 + d) * 2048 + mb;

    // pass 1: chunk-local scan from zero, cache dt/x in LDS
    float P = 1.f, h = 0.f;
    for (int lt = 0; lt < CLEN; lt += 4) {
        float4 dt4 = *(const float4*)(pdt + lt);
        float4 x4  = *(const float4*)(px + lt);
        if (n == 0) {
            *(float4*)&sdt[dl][ck][lt] = dt4;
            *(float4*)&sx[dl][ck][lt]  = x4;
        }
        float dta[4] = {dt4.x, dt4.y, dt4.z, dt4.w};
        float xa[4]  = {x4.x, x4.y, x4.z, x4.w};
#pragma unroll
        for (int j = 0; j < 4; ++j) {
            const float Bv = sp[(size_t)(mb + lt + j) * 96 + 64 + n];
            const float dA = __expf(dta[j] * An);
            P *= dA;
            h = fmaf(dA, h, dta[j] * Bv * xa[j]);
        }
    }
    Pc[dl][ck][n] = P;
    Hc[dl][ck][n] = h;
    __syncthreads();

    // combine: one thread per (dl, n), serial over the 8 chunks (exact)
    if (tid < 32) {
        const int dd = tid >> 4, nn = tid & 15;
        float hin = 0.f;
#pragma unroll
        for (int c = 0; c < NCHUNK; ++c) {
            Hin[dd][c][nn] = hin;
            hin = fmaf(Pc[dd][c][nn], hin, Hc[dd][c][nn]);
        }
    }
    __syncthreads();

    // pass 2: rescan with correct h_in from LDS-cached dt/x; emit yT bf16
    h = Hin[dl][ck][n];
    const float Dv = Dp[d];
    for (int lt = 0; lt < CLEN; lt += 4) {
        float4 g4 = *(const float4*)(pg + lt);
        float4 dt4 = *(const float4*)&sdt[dl][ck][lt];
        float4 x4  = *(const float4*)&sx[dl][ck][lt];
        float dta[4] = {dt4.x, dt4.y, dt4.z, dt4.w};
        float xa[4]  = {x4.x, x4.y, x4.z, x4.w};
        float ga[4]  = {g4.x, g4.y, g4.z, g4.w};
        ushort4 yv;
        unsigned short* yw = (unsigned short*)&yv;
#pragma unroll
        for (int j = 0; j < 4; ++j) {
            const size_t r = (size_t)(mb + lt + j) * 96;
            const float Bv = sp[r + 64 + n];
            const float Cv = sp[r + 80 + n];
            const float dA = __expf(dta[j] * An);
            h = fmaf(dA, h, dta[j] * Bv * xa[j]);
            float p = h * Cv;
            p += __shfl_xor(p, 1);
            p += __shfl_xor(p, 2);
            p += __shfl_xor(p, 4);
            p += __shfl_xor(p, 8);
            if (n == 0)
                yw[j] = f2bf(fmaf(xa[j], Dv, p) * siluf(ga[j]));
        }
        if (n == 0)
            *(ushort4*)(yT + (size_t)d * 2048 + mb + lt) = yv;
    }
}

extern "C" void kernel_launch(void* const* d_in, const int* in_sizes, int n_in,
                              void* d_out, int out_size, void* d_ws, size_t ws_size,
                              hipStream_t stream)
{
    const float* hs     = (const float*)d_in[0];
    const float* W_in   = (const float*)d_in[1];
    const float* conv_w = (const float*)d_in[2];
    const float* conv_b = (const float*)d_in[3];
    const float* W_x    = (const float*)d_in[4];
    const float* W_dt   = (const float*)d_in[5];
    const float* b_dt   = (const float*)d_in[6];
    const float* A_log  = (const float*)d_in[7];
    const float* Dp     = (const float*)d_in[8];
    const float* W_out  = (const float*)d_in[9];
    float* out = (float*)d_out;

    // workspace (~76.5 MB), with overlays:
    float* ws    = (float*)d_ws;
    float* projT = ws;                               // [4096][2048] f32; rows 0..2047 become dtT
    float* xT    = projT + (size_t)4096 * 2048;      // [2048][2048] f32
    float* ssm_p = xT + (size_t)2048 * 2048;         // [2048][96] f32
    unsigned short* hs_bf    = (unsigned short*)(ssm_p + (size_t)2048 * 96);
    unsigned short* W_in_bf  = hs_bf + (size_t)2048 * 1024;      // 4096*1024
    unsigned short* W_out_bf = W_in_bf + (size_t)4096 * 1024;    // 1024*2048
    unsigned short* W_x_bf   = W_out_bf + (size_t)1024 * 2048;   // 96*2048
    unsigned short* x_bf     = W_x_bf + (size_t)96 * 2048;       // [2048 m][2048 d]
    unsigned short* yT_bf    = hs_bf;                            // overlay (dead after proj GEMM)
    unsigned short* y_bf     = x_bf;                             // overlay (dead after ssm GEMM)
    float* dtT = projT;                                          // overlay rows 0..2047

    const int M = B_ * L_;  // 2048

    // 0. fp32 -> bf16 converts
    cvt_bf16<<<(2048 * 1024) / 1024, 256, 0, stream>>>(hs, hs_bf, 2048 * 1024);
    cvt_bf16<<<(4096 * 1024) / 1024, 256, 0, stream>>>(W_in, W_in_bf, 4096 * 1024);
    cvt_bf16<<<(1024 * 2048) / 1024, 256, 0, stream>>>(W_out, W_out_bf, 1024 * 2048);
    cvt_bf16<<<(96 * 2048) / 1024, 256, 0, stream>>>(W_x, W_x_bf, 96 * 2048);

    // 1. projT = (hs @ W_in^T)^T : [4096 e][2048 m] (bf16 MFMA, transposed store)
    gemm_bf16_nt<2><<<dim3(4096 / 128, M / 128, 1), 256, 0, stream>>>(
        hs_bf, W_in_bf, projT, 1024, 4096, 2048, 1024, 4096);

    // 2. conv + SiLU: projT rows 0..2047 -> xT[d][m] fp32 + x_bf[m][d] bf16
    conv_silu_kernel<<<dim3(D_ / 64, L_ / 64, B_), 256, 0, stream>>>(
        projT, conv_w, conv_b, xT, x_bf);

    // 3. ssm_p[m][96] = x @ W_x^T, K=2048 split 8 (bf16 MFMA, atomic fp32)
    hipMemsetAsync(ssm_p, 0, (size_t)M * 96 * sizeof(float), stream);
    gemm_bf16_nt<1><<<dim3(1, M / 128, 8), 256, 0, stream>>>(
        x_bf, W_x_bf, ssm_p, 2048, 96, 96, 256, 96);

    // 4. dtT[d][m] = softplus(W_dt @ dt_lr^T + b_dt[d])  (overlays projT rows 0..2047)
    gemm_nt_softplus<<<dim3(M / 128, 2048 / 128, 1), 256, 0, stream>>>(
        W_dt, ssm_p, dtT, 64, 64, 96, 2048, b_dt);

    // 5. chunked scan + fused gating -> yT[d][m] bf16
    scan_kernel<<<dim3(D_ / 2, B_), 256, 0, stream>>>(
        dtT, xT, projT, ssm_p, A_log, Dp, yT_bf);

    // 6. transpose yT -> y[m][d] bf16
    transpose_bf16<<<dim3(2048 / 64, 2048 / 64), 256, 0, stream>>>(yT_bf, y_bf);

    // 7. out = y @ W_out^T : [2048,1024], K=2048 split 2 (bf16 MFMA, atomic fp32)
    hipMemsetAsync(out, 0, (size_t)M * 1024 * sizeof(float), stream);
    gemm_bf16_nt<1><<<dim3(1024 / 128, M / 128, 2), 256, 0, stream>>>(
        y_bf, W_out_bf, out, 2048, 1024, 1024, 1024, 1024);
}